// Round 1
// baseline (536.509 us; speedup 1.0000x reference)
//
#include <hip/hip_runtime.h>
#include <math.h>

#define NN 50000
#define EE 800000

// ws layout (floats):
//   z   @ 0            (NN, padded region 65536)
//   U   @ 65536        (NN*64 = 3,200,000)
//   M   @ 3,265,536    (4096)
//   tq  @ 3,269,632    (NN*64 = 3,200,000)
//   hw  @ 6,469,632    (EE*16 = 12,800,000)
// total ~77 MB

// ---------- M = (W_q @ W_dot) @ W_lin_k^T  [64][64] ----------
__global__ __launch_bounds__(256) void fold_kernel(
    const float* __restrict__ Wq, const float* __restrict__ Wdot,
    const float* __restrict__ Wlk, float* __restrict__ M)
{
  __shared__ float tmp[2048];
  const int tid = threadIdx.x;
#pragma unroll
  for (int r = 0; r < 8; ++r) {
    int idx = tid + r * 256;
    int cin = idx >> 5, d = idx & 31;
    float a = 0.f;
    for (int j = 0; j < 32; ++j) a = fmaf(Wq[cin * 32 + j], Wdot[j * 32 + d], a);
    tmp[idx] = a;
  }
  __syncthreads();
#pragma unroll
  for (int r = 0; r < 16; ++r) {
    int idx = tid + r * 256;
    int cin = idx >> 6, c = idx & 63;
    float a = 0.f;
    for (int d = 0; d < 32; ++d) a = fmaf(tmp[cin * 32 + d], Wlk[c * 32 + d], a);
    M[idx] = a;  // M[cin][c]
  }
}

// ---------- radial MLP precompute: hw[e][0..7]=silu(eb@W1k), [8..15]=silu(eb@W1v) ----------
__global__ __launch_bounds__(256) void radial_kernel(
    const float* __restrict__ eb, const float* __restrict__ W1k,
    const float* __restrict__ W1v, float* __restrict__ hw)
{
  int e = blockIdx.x * 256 + threadIdx.x;
  if (e >= EE) return;
  const float4* eb4 = reinterpret_cast<const float4*>(eb);
  float4 q0 = eb4[e * 4 + 0], q1 = eb4[e * 4 + 1], q2 = eb4[e * 4 + 2], q3 = eb4[e * 4 + 3];
  float ebv[16] = {q0.x, q0.y, q0.z, q0.w, q1.x, q1.y, q1.z, q1.w,
                   q2.x, q2.y, q2.z, q2.w, q3.x, q3.y, q3.z, q3.w};
  float h[16];
#pragma unroll
  for (int j = 0; j < 16; ++j) h[j] = 0.f;
#pragma unroll
  for (int b = 0; b < 16; ++b) {
    float x = ebv[b];
#pragma unroll
    for (int j = 0; j < 8; ++j) {
      h[j]     = fmaf(x, W1k[b * 8 + j], h[j]);
      h[8 + j] = fmaf(x, W1v[b * 8 + j], h[8 + j]);
    }
  }
#pragma unroll
  for (int j = 0; j < 16; ++j) h[j] = h[j] / (1.f + __expf(-h[j]));  // silu
  float4* hw4 = reinterpret_cast<float4*>(hw);
  hw4[e * 4 + 0] = make_float4(h[0], h[1], h[2], h[3]);
  hw4[e * 4 + 1] = make_float4(h[4], h[5], h[6], h[7]);
  hw4[e * 4 + 2] = make_float4(h[8], h[9], h[10], h[11]);
  hw4[e * 4 + 3] = make_float4(h[12], h[13], h[14], h[15]);
}

// ---------- tq = nf @ M  [NN][64] ----------
__global__ __launch_bounds__(256) void tq_kernel(
    const float* __restrict__ nf, const float* __restrict__ M, float* __restrict__ tq)
{
  __shared__ float Ml[4096];
  __shared__ float nfl[64 * 68];
  const int tid = threadIdx.x;
  const int base = blockIdx.x * 64;
#pragma unroll
  for (int r = 0; r < 4; ++r) {
    int idx = tid + r * 256;
    reinterpret_cast<float4*>(Ml)[idx] = reinterpret_cast<const float4*>(M)[idx];
  }
#pragma unroll
  for (int r = 0; r < 4; ++r) {
    int idx = tid + r * 256;
    int row = idx >> 4, c4 = idx & 15;
    float4 v = make_float4(0.f, 0.f, 0.f, 0.f);
    if (base + row < NN) v = reinterpret_cast<const float4*>(nf)[(base + row) * 16 + c4];
    *reinterpret_cast<float4*>(&nfl[row * 68 + c4 * 4]) = v;
  }
  __syncthreads();
  const int to = tid & 15, tn = tid >> 4;
  float4 acc[4] = {make_float4(0,0,0,0), make_float4(0,0,0,0),
                   make_float4(0,0,0,0), make_float4(0,0,0,0)};
  for (int c = 0; c < 64; ++c) {
    float4 m = reinterpret_cast<const float4*>(Ml)[c * 16 + to];
#pragma unroll
    for (int i = 0; i < 4; ++i) {
      float x = nfl[(tn * 4 + i) * 68 + c];
      acc[i].x = fmaf(x, m.x, acc[i].x);
      acc[i].y = fmaf(x, m.y, acc[i].y);
      acc[i].z = fmaf(x, m.z, acc[i].z);
      acc[i].w = fmaf(x, m.w, acc[i].w);
    }
  }
#pragma unroll
  for (int i = 0; i < 4; ++i) {
    int n = base + tn * 4 + i;
    if (n < NN) reinterpret_cast<float4*>(tq)[n * 16 + to] = acc[i];
  }
}

// ---------- edge pass: one wave per edge; accumulate z[dst], U[dst][c] ----------
__global__ __launch_bounds__(256) void edge_kernel(
    const float* __restrict__ nf, const float* __restrict__ ea,
    const float* __restrict__ pos, const int* __restrict__ esrc,
    const int* __restrict__ edst, const float* __restrict__ W2k,
    const float* __restrict__ W2v, const float* __restrict__ hw,
    const float* __restrict__ tq, float* __restrict__ z, float* __restrict__ U)
{
  const int lane = threadIdx.x & 63;
  const int wid = (blockIdx.x * blockDim.x + threadIdx.x) >> 6;
  const int nw = (gridDim.x * blockDim.x) >> 6;
  const float4* W2k4 = reinterpret_cast<const float4*>(W2k);
  const float4* W2v4 = reinterpret_cast<const float4*>(W2v);
  const float4* hw4 = reinterpret_cast<const float4*>(hw);
  const float4* ea4p = reinterpret_cast<const float4*>(ea);

  for (int e = wid; e < EE; e += nw) {
    const int src = esrc[e];
    const int dst = edst[e];
    const float4 a4 = ea4p[e];
    const float4 k01 = hw4[e * 4 + 0];
    const float4 k23 = hw4[e * 4 + 1];
    const float4 v01 = hw4[e * 4 + 2];
    const float4 v23 = hw4[e * 4 + 3];
    const float hk[8] = {k01.x, k01.y, k01.z, k01.w, k23.x, k23.y, k23.z, k23.w};
    const float hv[8] = {v01.x, v01.y, v01.z, v01.w, v23.x, v23.y, v23.z, v23.w};
    float sk = 0.f, sv = 0.f;
#pragma unroll
    for (int h = 0; h < 8; ++h) {
      float4 wk = W2k4[h * 64 + lane];
      float dk = fmaf(wk.w, a4.w, fmaf(wk.z, a4.z, fmaf(wk.y, a4.y, wk.x * a4.x)));
      sk = fmaf(hk[h], dk, sk);
      float4 wv = W2v4[h * 64 + lane];
      float dv = fmaf(wv.w, a4.w, fmaf(wv.z, a4.z, fmaf(wv.y, a4.y, wv.x * a4.x)));
      sv = fmaf(hv[h], dv, sv);
    }
    const float x = nf[src * 64 + lane];
    const float tqv = tq[dst * 64 + lane];
    float part = x * sk * tqv;
#pragma unroll
    for (int off = 32; off; off >>= 1) part += __shfl_xor(part, off);
    const float score = 0.5f * part;  // /sqrt(A)=0.5 folded here
    const float dx = pos[dst * 3 + 0] - pos[src * 3 + 0];
    const float dy = pos[dst * 3 + 1] - pos[src * 3 + 1];
    const float dz = pos[dst * 3 + 2] - pos[src * 3 + 2];
    const float len = sqrtf(fmaf(dx, dx, fmaf(dy, dy, dz * dz)));
    const float arg = 10.f - 2.f * len;                       // 2*R_MAX*(1 - len/R_MAX)
    const float cut = (arg > 0.f) ? __expf(-1.f / arg) : 0.f; // soft_unit_step
    const float expv = cut * __expf(score);
    const float sexp = sqrtf(expv);
    if (lane == 0) unsafeAtomicAdd(&z[dst], expv);
    unsafeAtomicAdd(&U[dst * 64 + lane], sexp * x * sv);
  }
}

// ---------- final: out = 0.5*rsqrt(z) * (U @ Wlv) + einsum(nf,na,Wsc) ----------
__global__ __launch_bounds__(256) void final_kernel(
    const float* __restrict__ nf, const float* __restrict__ na,
    const float* __restrict__ Wlv, const float* __restrict__ Wsc,
    const float* __restrict__ U, const float* __restrict__ z,
    float* __restrict__ out)
{
  __shared__ float nfl[64 * 68];
  __shared__ float nal[64 * 17];
  __shared__ float4 Wlvl[1024];
  __shared__ float4 Wpl[1024];
  const int tid = threadIdx.x;
  const int base = blockIdx.x * 64;
#pragma unroll
  for (int r = 0; r < 4; ++r) {
    int idx = tid + r * 256;
    int row = idx >> 4, c4 = idx & 15;
    float4 v = make_float4(0.f, 0.f, 0.f, 0.f);
    if (base + row < NN) v = reinterpret_cast<const float4*>(nf)[(base + row) * 16 + c4];
    *reinterpret_cast<float4*>(&nfl[row * 68 + c4 * 4]) = v;
  }
#pragma unroll
  for (int r = 0; r < 4; ++r) {
    int idx = tid + r * 256;
    int row = idx >> 4, p = idx & 15;
    float v = 0.f;
    if (base + row < NN) v = na[(base + row) * 16 + p];
    nal[row * 17 + p] = v;
  }
#pragma unroll
  for (int r = 0; r < 4; ++r) {
    int idx = tid + r * 256;
    Wlvl[idx] = reinterpret_cast<const float4*>(Wlv)[idx];
  }
  const int to = tid & 15, tn = tid >> 4;
  float4 accs[4] = {make_float4(0,0,0,0), make_float4(0,0,0,0),
                    make_float4(0,0,0,0), make_float4(0,0,0,0)};
  for (int p = 0; p < 16; ++p) {
    __syncthreads();
#pragma unroll
    for (int r = 0; r < 4; ++r) {
      int idx = tid + r * 256;
      int c = idx >> 4, o4 = idx & 15;
      Wpl[c * 16 + o4] = reinterpret_cast<const float4*>(Wsc)[(c * 16 + p) * 16 + o4];
    }
    __syncthreads();
    float4 t[4] = {make_float4(0,0,0,0), make_float4(0,0,0,0),
                   make_float4(0,0,0,0), make_float4(0,0,0,0)};
    for (int c = 0; c < 64; ++c) {
      float4 w = Wpl[c * 16 + to];
#pragma unroll
      for (int i = 0; i < 4; ++i) {
        float xv = nfl[(tn * 4 + i) * 68 + c];
        t[i].x = fmaf(xv, w.x, t[i].x);
        t[i].y = fmaf(xv, w.y, t[i].y);
        t[i].z = fmaf(xv, w.z, t[i].z);
        t[i].w = fmaf(xv, w.w, t[i].w);
      }
    }
#pragma unroll
    for (int i = 0; i < 4; ++i) {
      float nap = nal[(tn * 4 + i) * 17 + p];
      accs[i].x = fmaf(nap, t[i].x, accs[i].x);
      accs[i].y = fmaf(nap, t[i].y, accs[i].y);
      accs[i].z = fmaf(nap, t[i].z, accs[i].z);
      accs[i].w = fmaf(nap, t[i].w, accs[i].w);
    }
  }
  // U @ Wlv
  int nrow[4];
#pragma unroll
  for (int i = 0; i < 4; ++i) {
    int n = base + tn * 4 + i;
    nrow[i] = (n < NN ? n : NN - 1) * 64;
  }
  float4 accu[4] = {make_float4(0,0,0,0), make_float4(0,0,0,0),
                    make_float4(0,0,0,0), make_float4(0,0,0,0)};
  for (int c = 0; c < 64; ++c) {
    float4 w = Wlvl[c * 16 + to];
#pragma unroll
    for (int i = 0; i < 4; ++i) {
      float uv = U[nrow[i] + c];
      accu[i].x = fmaf(uv, w.x, accu[i].x);
      accu[i].y = fmaf(uv, w.y, accu[i].y);
      accu[i].z = fmaf(uv, w.z, accu[i].z);
      accu[i].w = fmaf(uv, w.w, accu[i].w);
    }
  }
#pragma unroll
  for (int i = 0; i < 4; ++i) {
    int n = base + tn * 4 + i;
    if (n < NN) {
      float zz = z[n];
      float s = (zz > 0.f) ? 0.5f * rsqrtf(zz) : 0.f;  // /sqrt(A)=0.5 for v folded here
      float4 o;
      o.x = fmaf(accu[i].x, s, accs[i].x);
      o.y = fmaf(accu[i].y, s, accs[i].y);
      o.z = fmaf(accu[i].z, s, accs[i].z);
      o.w = fmaf(accu[i].w, s, accs[i].w);
      reinterpret_cast<float4*>(out)[n * 16 + to] = o;
    }
  }
}

extern "C" void kernel_launch(void* const* d_in, const int* in_sizes, int n_in,
                              void* d_out, int out_size, void* d_ws, size_t ws_size,
                              hipStream_t stream) {
  const float* nf   = (const float*)d_in[0];
  const float* na   = (const float*)d_in[1];
  const float* eb   = (const float*)d_in[2];
  const float* ea   = (const float*)d_in[3];
  const float* pos  = (const float*)d_in[4];
  const int*   esrc = (const int*)d_in[5];
  const int*   edst = (const int*)d_in[6];
  const float* Wq   = (const float*)d_in[7];
  const float* W1k  = (const float*)d_in[8];
  const float* W2k  = (const float*)d_in[9];
  const float* W1v  = (const float*)d_in[10];
  const float* W2v  = (const float*)d_in[11];
  const float* Wlk  = (const float*)d_in[12];
  const float* Wlv  = (const float*)d_in[13];
  const float* Wdot = (const float*)d_in[14];
  const float* Wsc  = (const float*)d_in[15];
  float* out = (float*)d_out;

  float* wsf = (float*)d_ws;
  float* z   = wsf;
  float* U   = wsf + 65536;
  float* M   = wsf + 65536 + (size_t)NN * 64;
  float* tq  = M + 4096;
  float* hw  = tq + (size_t)NN * 64;

  // zero the atomic accumulators (z + U)
  hipMemsetAsync(z, 0, (65536 + (size_t)NN * 64) * sizeof(float), stream);

  radial_kernel<<<(EE + 255) / 256, 256, 0, stream>>>(eb, W1k, W1v, hw);
  fold_kernel<<<1, 256, 0, stream>>>(Wq, Wdot, Wlk, M);
  tq_kernel<<<(NN + 63) / 64, 256, 0, stream>>>(nf, M, tq);
  edge_kernel<<<2048, 256, 0, stream>>>(nf, ea, pos, esrc, edst, W2k, W2v, hw, tq, z, U);
  final_kernel<<<(NN + 63) / 64, 256, 0, stream>>>(nf, na, Wlv, Wsc, U, z, out);
}

// Round 2
// 443.359 us; speedup vs baseline: 1.2101x; 1.2101x over previous
//
#include <hip/hip_runtime.h>
#include <math.h>

#define NN 50000
#define EE 800000
#define CPAD 66

typedef __attribute__((ext_vector_type(8))) short short8v;
typedef __attribute__((ext_vector_type(4))) float f32x4;

static __device__ __forceinline__ short bf16r(float x) {
  union { float f; unsigned u; } v; v.f = x;
  unsigned r = v.u + 0x7FFFu + ((v.u >> 16) & 1u);
  return (short)(r >> 16);
}

// ws layout (floats):
//   z    @ 0                      (65536)
//   U    @ 65536                  (3,200,000)
//   M    @ 3,265,536              (4096)
//   tq   @ 3,269,632              (3,200,000)
//   w2kT @ 6,469,632              (2048 bf16 = 1024 floats)
//   w2vT @ 6,470,656              (2048 bf16 = 1024 floats)
//   hw   @ 6,471,680              (EE*16 = 12,800,000)
// total ~77.09 MB

// ---------- M = (W_q @ W_dot) @ W_lin_k^T ; W2{k,v} -> transposed bf16 ----------
__global__ __launch_bounds__(256) void fold_kernel(
    const float* __restrict__ Wq, const float* __restrict__ Wdot,
    const float* __restrict__ Wlk, const float* __restrict__ W2k,
    const float* __restrict__ W2v, float* __restrict__ M,
    unsigned short* __restrict__ w2kT, unsigned short* __restrict__ w2vT)
{
  __shared__ float tmp[2048];
  const int tid = threadIdx.x;
#pragma unroll
  for (int r = 0; r < 8; ++r) {
    int idx = tid + r * 256;
    int cin = idx >> 5, d = idx & 31;
    float a = 0.f;
    for (int j = 0; j < 32; ++j) a = fmaf(Wq[cin * 32 + j], Wdot[j * 32 + d], a);
    tmp[idx] = a;
  }
  __syncthreads();
#pragma unroll
  for (int r = 0; r < 16; ++r) {
    int idx = tid + r * 256;
    int cin = idx >> 6, c = idx & 63;
    float a = 0.f;
    for (int d = 0; d < 32; ++d) a = fmaf(tmp[cin * 32 + d], Wlk[c * 32 + d], a);
    M[idx] = a;  // M[cin][c]
  }
  // W2' transposed bf16: w2T[c*32 + (h*4+a)] = W2[h][c][a]
#pragma unroll
  for (int r = 0; r < 8; ++r) {
    int idx = tid + r * 256;
    int c = idx >> 5, k = idx & 31, h = k >> 2, a = k & 3;
    w2kT[idx] = (unsigned short)bf16r(W2k[h * 256 + c * 4 + a]);
    w2vT[idx] = (unsigned short)bf16r(W2v[h * 256 + c * 4 + a]);
  }
}

// ---------- radial MLP precompute: hw[e][0..7]=silu(eb@W1k), [8..15]=silu(eb@W1v) ----------
__global__ __launch_bounds__(256) void radial_kernel(
    const float* __restrict__ eb, const float* __restrict__ W1k,
    const float* __restrict__ W1v, float* __restrict__ hw)
{
  int e = blockIdx.x * 256 + threadIdx.x;
  if (e >= EE) return;
  const float4* eb4 = reinterpret_cast<const float4*>(eb);
  float4 q0 = eb4[e * 4 + 0], q1 = eb4[e * 4 + 1], q2 = eb4[e * 4 + 2], q3 = eb4[e * 4 + 3];
  float ebv[16] = {q0.x, q0.y, q0.z, q0.w, q1.x, q1.y, q1.z, q1.w,
                   q2.x, q2.y, q2.z, q2.w, q3.x, q3.y, q3.z, q3.w};
  float h[16];
#pragma unroll
  for (int j = 0; j < 16; ++j) h[j] = 0.f;
#pragma unroll
  for (int b = 0; b < 16; ++b) {
    float x = ebv[b];
#pragma unroll
    for (int j = 0; j < 8; ++j) {
      h[j]     = fmaf(x, W1k[b * 8 + j], h[j]);
      h[8 + j] = fmaf(x, W1v[b * 8 + j], h[8 + j]);
    }
  }
#pragma unroll
  for (int j = 0; j < 16; ++j) h[j] = h[j] / (1.f + __expf(-h[j]));  // silu
  float4* hw4 = reinterpret_cast<float4*>(hw);
  hw4[e * 4 + 0] = make_float4(h[0], h[1], h[2], h[3]);
  hw4[e * 4 + 1] = make_float4(h[4], h[5], h[6], h[7]);
  hw4[e * 4 + 2] = make_float4(h[8], h[9], h[10], h[11]);
  hw4[e * 4 + 3] = make_float4(h[12], h[13], h[14], h[15]);
}

// ---------- tq = nf @ M  [NN][64] ----------
__global__ __launch_bounds__(256) void tq_kernel(
    const float* __restrict__ nf, const float* __restrict__ M, float* __restrict__ tq)
{
  __shared__ float Ml[4096];
  __shared__ float nfl[64 * 68];
  const int tid = threadIdx.x;
  const int base = blockIdx.x * 64;
#pragma unroll
  for (int r = 0; r < 4; ++r) {
    int idx = tid + r * 256;
    reinterpret_cast<float4*>(Ml)[idx] = reinterpret_cast<const float4*>(M)[idx];
  }
#pragma unroll
  for (int r = 0; r < 4; ++r) {
    int idx = tid + r * 256;
    int row = idx >> 4, c4 = idx & 15;
    float4 v = make_float4(0.f, 0.f, 0.f, 0.f);
    if (base + row < NN) v = reinterpret_cast<const float4*>(nf)[(base + row) * 16 + c4];
    *reinterpret_cast<float4*>(&nfl[row * 68 + c4 * 4]) = v;
  }
  __syncthreads();
  const int to = tid & 15, tn = tid >> 4;
  float4 acc[4] = {make_float4(0,0,0,0), make_float4(0,0,0,0),
                   make_float4(0,0,0,0), make_float4(0,0,0,0)};
  for (int c = 0; c < 64; ++c) {
    float4 m = reinterpret_cast<const float4*>(Ml)[c * 16 + to];
#pragma unroll
    for (int i = 0; i < 4; ++i) {
      float x = nfl[(tn * 4 + i) * 68 + c];
      acc[i].x = fmaf(x, m.x, acc[i].x);
      acc[i].y = fmaf(x, m.y, acc[i].y);
      acc[i].z = fmaf(x, m.z, acc[i].z);
      acc[i].w = fmaf(x, m.w, acc[i].w);
    }
  }
#pragma unroll
  for (int i = 0; i < 4; ++i) {
    int n = base + tn * 4 + i;
    if (n < NN) reinterpret_cast<float4*>(tq)[n * 16 + to] = acc[i];
  }
}

// ---------- edge pass (MFMA): 64 edges/block, 4 waves x 16 edges ----------
__global__ __launch_bounds__(256) void edge_kernel(
    const float* __restrict__ nf, const float* __restrict__ ea,
    const float* __restrict__ pos, const int* __restrict__ esrc,
    const int* __restrict__ edst, const float* __restrict__ hw,
    const float* __restrict__ tq, const unsigned short* __restrict__ w2kT,
    const unsigned short* __restrict__ w2vT,
    float* __restrict__ z, float* __restrict__ U)
{
  __shared__ float ys[64 * CPAD];   // x_src * tq_dst
  __shared__ float xs[64 * CPAD];   // x_src
  __shared__ int   ed[64];
  __shared__ float cl[64];
  const int tid  = threadIdx.x;
  const int lane = tid & 63;
  const int lo = lane & 15, hi = lane >> 4;
  const int e0 = blockIdx.x * 64;

  // B fragments (loop-invariant): B[k][col]; lane: col=16t+lo, k=hi*8+j
  short8v bk[4], bv[4];
#pragma unroll
  for (int t = 0; t < 4; ++t) {
    bk[t] = *reinterpret_cast<const short8v*>(&w2kT[(16 * t + lo) * 32 + hi * 8]);
    bv[t] = *reinterpret_cast<const short8v*>(&w2vT[(16 * t + lo) * 32 + hi * 8]);
  }

  if (tid < 64) {
    int s = esrc[e0 + tid], d = edst[e0 + tid];
    ed[tid] = d;
    float dx = pos[d * 3 + 0] - pos[s * 3 + 0];
    float dy = pos[d * 3 + 1] - pos[s * 3 + 1];
    float dz = pos[d * 3 + 2] - pos[s * 3 + 2];
    float len = sqrtf(fmaf(dx, dx, fmaf(dy, dy, dz * dz)));
    float arg = 10.f - 2.f * len;                         // 2*R_MAX*(1 - len/R_MAX)
    cl[tid] = (arg > 0.f) ? __expf(-1.f / arg) : 0.f;     // soft_unit_step
  }
#pragma unroll
  for (int r = 0; r < 4; ++r) {
    int idx = tid + r * 256;
    int e = idx >> 4, c4 = idx & 15;
    int s = esrc[e0 + e], d = edst[e0 + e];
    float4 xv = reinterpret_cast<const float4*>(nf)[s * 16 + c4];
    float4 tv = reinterpret_cast<const float4*>(tq)[d * 16 + c4];
    float* xp = &xs[e * CPAD + c4 * 4];
    xp[0] = xv.x; xp[1] = xv.y; xp[2] = xv.z; xp[3] = xv.w;
    float* yp = &ys[e * CPAD + c4 * 4];
    yp[0] = xv.x * tv.x; yp[1] = xv.y * tv.y; yp[2] = xv.z * tv.z; yp[3] = xv.w * tv.w;
  }
  __syncthreads();

  // A fragments built on the fly: A[row=edge][k=h*4+a] = h[row][h]*ea[row][a]
  const int w = tid >> 6;
  const int eg = e0 + 16 * w + lo;                  // A-row edge for this lane
  float2 hk2 = *reinterpret_cast<const float2*>(&hw[eg * 16 + hi * 2]);
  float2 hv2 = *reinterpret_cast<const float2*>(&hw[eg * 16 + 8 + hi * 2]);
  float4 a4 = reinterpret_cast<const float4*>(ea)[eg];
  float af0 = a4.x, af1 = a4.y, af2 = a4.z, af3 = a4.w;
  short8v ak, av;
  ak[0] = bf16r(hk2.x * af0); ak[1] = bf16r(hk2.x * af1);
  ak[2] = bf16r(hk2.x * af2); ak[3] = bf16r(hk2.x * af3);
  ak[4] = bf16r(hk2.y * af0); ak[5] = bf16r(hk2.y * af1);
  ak[6] = bf16r(hk2.y * af2); ak[7] = bf16r(hk2.y * af3);
  av[0] = bf16r(hv2.x * af0); av[1] = bf16r(hv2.x * af1);
  av[2] = bf16r(hv2.x * af2); av[3] = bf16r(hv2.x * af3);
  av[4] = bf16r(hv2.y * af0); av[5] = bf16r(hv2.y * af1);
  av[6] = bf16r(hv2.y * af2); av[7] = bf16r(hv2.y * af3);

  f32x4 zero = {0.f, 0.f, 0.f, 0.f};
  f32x4 ack[4], acv[4];
#pragma unroll
  for (int t = 0; t < 4; ++t) {
    ack[t] = __builtin_amdgcn_mfma_f32_16x16x32_bf16(ak, bk[t], zero, 0, 0, 0);
    acv[t] = __builtin_amdgcn_mfma_f32_16x16x32_bf16(av, bv[t], zero, 0, 0, 0);
  }

  // score: per C-row (edge erow+i), col = 16t+lo
  const int erow = 16 * w + 4 * hi;
  float p0, p1, p2, p3;
  {
    const float* y0 = &ys[(erow + 0) * CPAD + lo];
    const float* y1 = &ys[(erow + 1) * CPAD + lo];
    const float* y2 = &ys[(erow + 2) * CPAD + lo];
    const float* y3 = &ys[(erow + 3) * CPAD + lo];
    p0 = y0[0]*ack[0][0] + y0[16]*ack[1][0] + y0[32]*ack[2][0] + y0[48]*ack[3][0];
    p1 = y1[0]*ack[0][1] + y1[16]*ack[1][1] + y1[32]*ack[2][1] + y1[48]*ack[3][1];
    p2 = y2[0]*ack[0][2] + y2[16]*ack[1][2] + y2[32]*ack[2][2] + y2[48]*ack[3][2];
    p3 = y3[0]*ack[0][3] + y3[16]*ack[1][3] + y3[32]*ack[2][3] + y3[48]*ack[3][3];
  }
#pragma unroll
  for (int off = 1; off < 16; off <<= 1) {
    p0 += __shfl_xor(p0, off);
    p1 += __shfl_xor(p1, off);
    p2 += __shfl_xor(p2, off);
    p3 += __shfl_xor(p3, off);
  }
  // expv + sqrt (0.5 = 1/sqrt(A) folded into score scale)
  float ev0 = cl[erow + 0] * __expf(0.5f * p0);
  float ev1 = cl[erow + 1] * __expf(0.5f * p1);
  float ev2 = cl[erow + 2] * __expf(0.5f * p2);
  float ev3 = cl[erow + 3] * __expf(0.5f * p3);
  float se0 = sqrtf(ev0), se1 = sqrtf(ev1), se2 = sqrtf(ev2), se3 = sqrtf(ev3);
  if (lo < 4) {
    float ev = (lo == 0) ? ev0 : (lo == 1) ? ev1 : (lo == 2) ? ev2 : ev3;
    unsafeAtomicAdd(&z[ed[erow + lo]], ev);
  }
  // U[dst][c] += sexp * x_src[c] * sv[c]
#pragma unroll
  for (int i = 0; i < 4; ++i) {
    const float se = (i == 0) ? se0 : (i == 1) ? se1 : (i == 2) ? se2 : se3;
    const int d = ed[erow + i];
    const float* xr = &xs[(erow + i) * CPAD + lo];
#pragma unroll
    for (int t = 0; t < 4; ++t) {
      unsafeAtomicAdd(&U[d * 64 + 16 * t + lo], se * xr[16 * t] * acv[t][i]);
    }
  }
}

// ---------- final: out = 0.5*rsqrt(z) * (U @ Wlv) + einsum(nf,na,Wsc) ----------
__global__ __launch_bounds__(256) void final_kernel(
    const float* __restrict__ nf, const float* __restrict__ na,
    const float* __restrict__ Wlv, const float* __restrict__ Wsc,
    const float* __restrict__ U, const float* __restrict__ z,
    float* __restrict__ out)
{
  __shared__ float nfl[64 * 68];
  __shared__ float nal[64 * 17];
  __shared__ float4 Wlvl[1024];
  __shared__ float4 Wpl[1024];
  const int tid = threadIdx.x;
  const int base = blockIdx.x * 64;
#pragma unroll
  for (int r = 0; r < 4; ++r) {
    int idx = tid + r * 256;
    int row = idx >> 4, c4 = idx & 15;
    float4 v = make_float4(0.f, 0.f, 0.f, 0.f);
    if (base + row < NN) v = reinterpret_cast<const float4*>(nf)[(base + row) * 16 + c4];
    *reinterpret_cast<float4*>(&nfl[row * 68 + c4 * 4]) = v;
  }
#pragma unroll
  for (int r = 0; r < 4; ++r) {
    int idx = tid + r * 256;
    int row = idx >> 4, p = idx & 15;
    float v = 0.f;
    if (base + row < NN) v = na[(base + row) * 16 + p];
    nal[row * 17 + p] = v;
  }
#pragma unroll
  for (int r = 0; r < 4; ++r) {
    int idx = tid + r * 256;
    Wlvl[idx] = reinterpret_cast<const float4*>(Wlv)[idx];
  }
  const int to = tid & 15, tn = tid >> 4;
  float4 accs[4] = {make_float4(0,0,0,0), make_float4(0,0,0,0),
                    make_float4(0,0,0,0), make_float4(0,0,0,0)};
  for (int p = 0; p < 16; ++p) {
    __syncthreads();
#pragma unroll
    for (int r = 0; r < 4; ++r) {
      int idx = tid + r * 256;
      int c = idx >> 4, o4 = idx & 15;
      Wpl[c * 16 + o4] = reinterpret_cast<const float4*>(Wsc)[(c * 16 + p) * 16 + o4];
    }
    __syncthreads();
    float4 t[4] = {make_float4(0,0,0,0), make_float4(0,0,0,0),
                   make_float4(0,0,0,0), make_float4(0,0,0,0)};
    for (int c = 0; c < 64; ++c) {
      float4 w = Wpl[c * 16 + to];
#pragma unroll
      for (int i = 0; i < 4; ++i) {
        float xv = nfl[(tn * 4 + i) * 68 + c];
        t[i].x = fmaf(xv, w.x, t[i].x);
        t[i].y = fmaf(xv, w.y, t[i].y);
        t[i].z = fmaf(xv, w.z, t[i].z);
        t[i].w = fmaf(xv, w.w, t[i].w);
      }
    }
#pragma unroll
    for (int i = 0; i < 4; ++i) {
      float nap = nal[(tn * 4 + i) * 17 + p];
      accs[i].x = fmaf(nap, t[i].x, accs[i].x);
      accs[i].y = fmaf(nap, t[i].y, accs[i].y);
      accs[i].z = fmaf(nap, t[i].z, accs[i].z);
      accs[i].w = fmaf(nap, t[i].w, accs[i].w);
    }
  }
  // U @ Wlv
  int nrow[4];
#pragma unroll
  for (int i = 0; i < 4; ++i) {
    int n = base + tn * 4 + i;
    nrow[i] = (n < NN ? n : NN - 1) * 64;
  }
  float4 accu[4] = {make_float4(0,0,0,0), make_float4(0,0,0,0),
                    make_float4(0,0,0,0), make_float4(0,0,0,0)};
  for (int c = 0; c < 64; ++c) {
    float4 w = Wlvl[c * 16 + to];
#pragma unroll
    for (int i = 0; i < 4; ++i) {
      float uv = U[nrow[i] + c];
      accu[i].x = fmaf(uv, w.x, accu[i].x);
      accu[i].y = fmaf(uv, w.y, accu[i].y);
      accu[i].z = fmaf(uv, w.z, accu[i].z);
      accu[i].w = fmaf(uv, w.w, accu[i].w);
    }
  }
#pragma unroll
  for (int i = 0; i < 4; ++i) {
    int n = base + tn * 4 + i;
    if (n < NN) {
      float zz = z[n];
      float s = (zz > 0.f) ? 0.5f * rsqrtf(zz) : 0.f;  // /sqrt(A)=0.5 for v folded here
      float4 o;
      o.x = fmaf(accu[i].x, s, accs[i].x);
      o.y = fmaf(accu[i].y, s, accs[i].y);
      o.z = fmaf(accu[i].z, s, accs[i].z);
      o.w = fmaf(accu[i].w, s, accs[i].w);
      reinterpret_cast<float4*>(out)[n * 16 + to] = o;
    }
  }
}

extern "C" void kernel_launch(void* const* d_in, const int* in_sizes, int n_in,
                              void* d_out, int out_size, void* d_ws, size_t ws_size,
                              hipStream_t stream) {
  const float* nf   = (const float*)d_in[0];
  const float* na   = (const float*)d_in[1];
  const float* eb   = (const float*)d_in[2];
  const float* ea   = (const float*)d_in[3];
  const float* pos  = (const float*)d_in[4];
  const int*   esrc = (const int*)d_in[5];
  const int*   edst = (const int*)d_in[6];
  const float* Wq   = (const float*)d_in[7];
  const float* W1k  = (const float*)d_in[8];
  const float* W2k  = (const float*)d_in[9];
  const float* W1v  = (const float*)d_in[10];
  const float* W2v  = (const float*)d_in[11];
  const float* Wlk  = (const float*)d_in[12];
  const float* Wlv  = (const float*)d_in[13];
  const float* Wdot = (const float*)d_in[14];
  const float* Wsc  = (const float*)d_in[15];
  float* out = (float*)d_out;

  const size_t NN64 = (size_t)NN * 64;
  float* wsf = (float*)d_ws;
  float* z   = wsf;
  float* U   = wsf + 65536;
  float* M   = wsf + 65536 + NN64;
  float* tq  = M + 4096;
  unsigned short* w2kT = (unsigned short*)(tq + NN64);
  unsigned short* w2vT = w2kT + 2048;
  float* hw  = (float*)(w2vT + 2048);

  // zero the atomic accumulators (z + U)
  hipMemsetAsync(z, 0, (65536 + NN64) * sizeof(float), stream);

  radial_kernel<<<(EE + 255) / 256, 256, 0, stream>>>(eb, W1k, W1v, hw);
  fold_kernel<<<1, 256, 0, stream>>>(Wq, Wdot, Wlk, W2k, W2v, M, w2kT, w2vT);
  tq_kernel<<<(NN + 63) / 64, 256, 0, stream>>>(nf, M, tq);
  edge_kernel<<<EE / 64, 256, 0, stream>>>(nf, ea, pos, esrc, edst, hw, tq, w2kT, w2vT, z, U);
  final_kernel<<<(NN + 63) / 64, 256, 0, stream>>>(nf, na, Wlv, Wsc, U, z, out);
}